// Round 4
// baseline (434.198 us; speedup 1.0000x reference)
//
#include <hip/hip_runtime.h>

// VectorQuantizer: latents [32,64,64,64] f32, embedding [1024,64] f32.
// Outputs flat in d_out (f32): vq_loss @0, perplexity @1,
// out [32,64,64,64] @2, one_hot [131072,1024] @8388610.
//
// N = 131072 rows (b*4096 + h*64 + w), D = 64, K = 1024.
// Block = 256 threads = 4 waves; block owns 64 rows; wave wq handles
// k-quarter [wq*256, wq*256+256). Argmin combined via LDS (ascending wq,
// strict < => first-index tie-break, matches np.argmin exactly).
//
// x[64] is pinned in VGPRs via empty inline-asm (+v) — without it LLVM
// rematerializes x as per-tile global re-loads (rounds 2/3: VGPR 64-68,
// ~150-250us of excess VMEM+addr VALU). launch_bounds(256,3) caps ~170 VGPR.
//
// ws float layout:
//   ne      [0, 1024)      ||e_k||^2 (numpy pairwise-8 order)
//   counts  [1024, 2048)   uint32 histogram of inds
//   partials[2048, 10240)  per-wave f32 loss partial sums (8192)

#define KEMB 1024
#define DEMB 64

__global__ __launch_bounds__(256) void vq_prep(const float* __restrict__ emb,
                                               float* __restrict__ ne,
                                               unsigned int* __restrict__ counts) {
#pragma clang fp contract(off)
    int k = blockIdx.x * 256 + threadIdx.x;
    if (k >= KEMB) return;
    counts[k] = 0u;
    float v[DEMB];
#pragma unroll
    for (int d = 0; d < DEMB; ++d) v[d] = emb[k * DEMB + d];
    // numpy pairwise sum, n=64: 8 strided accumulators then tree combine
    float r[8];
#pragma unroll
    for (int j = 0; j < 8; ++j) r[j] = v[j] * v[j];
#pragma unroll
    for (int i = 8; i < 64; i += 8)
#pragma unroll
        for (int j = 0; j < 8; ++j) r[j] = r[j] + v[i + j] * v[i + j];
    ne[k] = ((r[0] + r[1]) + (r[2] + r[3])) + ((r[4] + r[5]) + (r[6] + r[7]));
}

__global__ __launch_bounds__(256, 3) void vq_main(const float* __restrict__ lat,
                                                  const float* __restrict__ emb,
                                                  const float* __restrict__ ne,
                                                  float* __restrict__ outq,
                                                  float* __restrict__ onehot,
                                                  unsigned int* __restrict__ counts,
                                                  float* __restrict__ partials) {
    __shared__ float sbest[4][64];
    __shared__ int sbi[4][64];

    const int lane = threadIdx.x & 63;
    const int wq = __builtin_amdgcn_readfirstlane(threadIdx.x >> 6); // 0..3, SGPR
    const int n0 = blockIdx.x * 64;       // first row of this block
    const int bimg = n0 >> 12;            // 4096 rows per image
    const int hw0 = n0 & 4095;

    // Load this lane's latent vector: lat[bimg, d, hw0+lane] (4x redundant
    // across the block's 4 waves; L2-hot). Coalesced 256B per d.
    const float* latp = lat + (size_t)bimg * (DEMB * 4096) + hw0 + lane;
    float x[DEMB];
#pragma unroll
    for (int d = 0; d < DEMB; ++d) x[d] = latp[(size_t)d * 4096];

    // Pin x in VGPRs: the asm def cannot be rematerialized, so the k-loop
    // and epilogue reuse registers instead of re-loading from global.
#pragma unroll
    for (int d = 0; d < DEMB; ++d) asm volatile("" : "+v"(x[d]));

    // nx = ||x||^2 in numpy pairwise-8 order, no FMA contraction.
    float nx;
    {
#pragma clang fp contract(off)
        float r[8];
#pragma unroll
        for (int j = 0; j < 8; ++j) r[j] = x[j] * x[j];
#pragma unroll
        for (int i = 8; i < 64; i += 8)
#pragma unroll
            for (int j = 0; j < 8; ++j) r[j] = r[j] + x[i + j] * x[i + j];
        nx = ((r[0] + r[1]) + (r[2] + r[3])) + ((r[4] + r[5]) + (r[6] + r[7]));
    }

    // k-quarter loop: 64 tiles of 4 contiguous codes (1KB of emb per tile,
    // wave-uniform addresses). dot = sequential FMA chain over d per code
    // (matches np BLAS micro-kernel order); 4 independent chains -> 8-cyc
    // same-chain spacing > FMA latency -> full issue rate at 3 waves/EU.
    // Interleaved: 2 one_hot zero-fill stores per tile (overlap HBM w/ VALU).
    float2* ohf2 = (float2*)onehot;
    const float2 z2 = make_float2(0.0f, 0.0f);
    float best = __builtin_inff();
    int bi = 0;
    const int kbase = wq << 8;
    const float4* ep = (const float4*)(emb + (size_t)kbase * DEMB);
    const float* nep = ne + kbase;
    for (int t = 0; t < 64; ++t) {
        float a0 = 0.0f, a1 = 0.0f, a2 = 0.0f, a3 = 0.0f;
#pragma unroll
        for (int d4 = 0; d4 < 16; ++d4) {
            float4 v0 = ep[d4], v1 = ep[16 + d4], v2 = ep[32 + d4], v3 = ep[48 + d4];
            a0 = __builtin_fmaf(x[4 * d4 + 0], v0.x, a0);
            a0 = __builtin_fmaf(x[4 * d4 + 1], v0.y, a0);
            a0 = __builtin_fmaf(x[4 * d4 + 2], v0.z, a0);
            a0 = __builtin_fmaf(x[4 * d4 + 3], v0.w, a0);
            a1 = __builtin_fmaf(x[4 * d4 + 0], v1.x, a1);
            a1 = __builtin_fmaf(x[4 * d4 + 1], v1.y, a1);
            a1 = __builtin_fmaf(x[4 * d4 + 2], v1.z, a1);
            a1 = __builtin_fmaf(x[4 * d4 + 3], v1.w, a1);
            a2 = __builtin_fmaf(x[4 * d4 + 0], v2.x, a2);
            a2 = __builtin_fmaf(x[4 * d4 + 1], v2.y, a2);
            a2 = __builtin_fmaf(x[4 * d4 + 2], v2.z, a2);
            a2 = __builtin_fmaf(x[4 * d4 + 3], v2.w, a2);
            a3 = __builtin_fmaf(x[4 * d4 + 0], v3.x, a3);
            a3 = __builtin_fmaf(x[4 * d4 + 1], v3.y, a3);
            a3 = __builtin_fmaf(x[4 * d4 + 2], v3.z, a3);
            a3 = __builtin_fmaf(x[4 * d4 + 3], v3.w, a3);
        }
        {
#pragma clang fp contract(off)
            const int k0 = kbase + (t << 2);
            float d0 = (nx + nep[t * 4 + 0]) - 2.0f * a0;
            float d1 = (nx + nep[t * 4 + 1]) - 2.0f * a1;
            float d2 = (nx + nep[t * 4 + 2]) - 2.0f * a2;
            float d3 = (nx + nep[t * 4 + 3]) - 2.0f * a3;
            if (d0 < best) { best = d0; bi = k0 + 0; }
            if (d1 < best) { best = d1; bi = k0 + 1; }
            if (d2 < best) { best = d2; bi = k0 + 2; }
            if (d3 < best) { best = d3; bi = k0 + 3; }
        }
        ep += 64;
        // zero-fill: wave wq covers one_hot chunks [wq*128, wq*128+128) of
        // row (n0+t); one row per tile, 64 tiles = all 64 rows.
        float2* zp = ohf2 + (((size_t)(n0 + t)) << 9) + (wq << 7) + lane;
        zp[0] = z2;
        zp[64] = z2;
    }

    sbest[wq][lane] = best;
    sbi[wq][lane] = bi;
    __syncthreads();   // also drains vmcnt -> all zero stores complete

    // combine quarters in ascending order, strict < (first-index tie-break)
    float bb = sbest[0][lane];
    int ib = sbi[0][lane];
#pragma unroll
    for (int qq = 1; qq < 4; ++qq) {
        float c = sbest[qq][lane];
        int ci = sbi[qq][lane];
        if (c < bb) { bb = c; ib = ci; }
    }

    if (wq == 0) {
        onehot[(size_t)(n0 + lane) * KEMB + ib] = 1.0f;
        atomicAdd(&counts[ib], 1u);
    }

    // out = lat + (q - lat); loss partial. Wave wq handles d in [wq*16,+16).
    float lsum = 0.0f;
    const size_t obase = (size_t)bimg * (DEMB * 4096) + hw0 + lane;
    {
#pragma clang fp contract(off)
#define OUT_LOSS(Q)                                                          \
        {                                                                    \
            const float4* eq4 = (const float4*)(emb + (size_t)ib * DEMB + (Q) * 16); \
            _Pragma("unroll")                                                \
            for (int c4 = 0; c4 < 4; ++c4) {                                 \
                float4 qv = eq4[c4];                                         \
                float xv0 = x[(Q) * 16 + 4 * c4 + 0];                        \
                float xv1 = x[(Q) * 16 + 4 * c4 + 1];                        \
                float xv2 = x[(Q) * 16 + 4 * c4 + 2];                        \
                float xv3 = x[(Q) * 16 + 4 * c4 + 3];                        \
                float f0 = qv.x - xv0, f1 = qv.y - xv1;                      \
                float f2 = qv.z - xv2, f3 = qv.w - xv3;                      \
                outq[obase + (size_t)((Q) * 16 + 4 * c4 + 0) * 4096] = xv0 + f0; \
                outq[obase + (size_t)((Q) * 16 + 4 * c4 + 1) * 4096] = xv1 + f1; \
                outq[obase + (size_t)((Q) * 16 + 4 * c4 + 2) * 4096] = xv2 + f2; \
                outq[obase + (size_t)((Q) * 16 + 4 * c4 + 3) * 4096] = xv3 + f3; \
                lsum = lsum + f0 * f0;                                       \
                lsum = lsum + f1 * f1;                                       \
                lsum = lsum + f2 * f2;                                       \
                lsum = lsum + f3 * f3;                                       \
            }                                                                \
        }
        switch (wq) {
            case 0: OUT_LOSS(0); break;
            case 1: OUT_LOSS(1); break;
            case 2: OUT_LOSS(2); break;
            default: OUT_LOSS(3); break;
        }
#undef OUT_LOSS
    }
#pragma unroll
    for (int off = 32; off > 0; off >>= 1) lsum += __shfl_xor(lsum, off, 64);
    if (lane == 0) partials[blockIdx.x * 4 + wq] = lsum;
}

__global__ __launch_bounds__(1024) void vq_final(const unsigned int* __restrict__ counts,
                                                 const float* __restrict__ partials,
                                                 float* __restrict__ out01) {
    __shared__ float sb[1024];
    int t = threadIdx.x;
    // vq_loss: deterministic tree over 8192 per-wave partials
    float s = 0.0f;
#pragma unroll
    for (int i = 0; i < 8; ++i) s += partials[t + 1024 * i];
    sb[t] = s;
    __syncthreads();
    for (int off = 512; off > 0; off >>= 1) {
        if (t < off) sb[t] = sb[t] + sb[t + off];
        __syncthreads();
    }
    if (t == 0) {
        float m = sb[0] / 8388608.0f;   // mean of (q-lat)^2
        out01[0] = m * 0.25f + m;       // BETA*commitment + embedding
    }
    __syncthreads();
    // perplexity: avg_probs = counts / N (exact), entropy tree, exp.
    float p = (float)counts[t] * (1.0f / 131072.0f);
    sb[t] = p * logf(p + 1e-10f);
    __syncthreads();
    for (int off = 512; off > 0; off >>= 1) {
        if (t < off) sb[t] = sb[t] + sb[t + off];
        __syncthreads();
    }
    if (t == 0) out01[1] = expf(-sb[0]);
}

extern "C" void kernel_launch(void* const* d_in, const int* in_sizes, int n_in,
                              void* d_out, int out_size, void* d_ws, size_t ws_size,
                              hipStream_t stream) {
    const float* lat = (const float*)d_in[0];
    const float* emb = (const float*)d_in[1];
    float* out = (float*)d_out;
    float* ws = (float*)d_ws;

    float* ne = ws;
    unsigned int* counts = (unsigned int*)(ws + 1024);
    float* partials = ws + 2048;

    float* outq = out + 2;
    float* onehot = out + 2 + 8388608;

    vq_prep<<<4, 256, 0, stream>>>(emb, ne, counts);
    vq_main<<<2048, 256, 0, stream>>>(lat, emb, ne, outq, onehot, counts, partials);
    vq_final<<<1, 1024, 0, stream>>>(counts, partials, out);
}

// Round 5
// 309.213 us; speedup vs baseline: 1.4042x; 1.4042x over previous
//
#include <hip/hip_runtime.h>

// VectorQuantizer: latents [32,64,64,64] f32, embedding [1024,64] f32.
// Outputs flat in d_out (f32): vq_loss @0, perplexity @1,
// out [32,64,64,64] @2, one_hot [131072,1024] @8388610.
//
// N = 131072 rows (b*4096 + h*64 + w), D = 64, K = 1024.
// Block = 256 threads = 4 waves; block owns 64 rows; wave wq handles
// k-quarter [wq*256, wq*256+256). Argmin combined via LDS (ascending wq,
// strict < => first-index tie-break, matches np.argmin exactly).
//
// ROUND-5 RESTRUCTURE: x lives in LDS, not VGPRs. Rounds 2-4 proved LLVM
// refuses to keep x[64] register-resident (VGPR stuck at 64-68; per-tile
// global re-loads = ~3x the FMA-floor VALU work; asm pin + launch_bounds
// hints all ineffective). LDS tile [64 rows][stride 65] -> bank (lane+d)%32
// = 2-way = free; explicit per-tile ds_reads are cheap (DS pipe overlaps
// VALU) and make codegen deterministic.
//
// ws float layout:
//   ne      [0, 1024)      ||e_k||^2 (numpy pairwise-8 order)
//   counts  [1024, 2048)   uint32 histogram of inds
//   partials[2048, 10240)  per-wave f32 loss partial sums (8192)

#define KEMB 1024
#define DEMB 64
#define XS 65   // LDS x row stride (floats); odd => conflict-free

__global__ __launch_bounds__(256) void vq_prep(const float* __restrict__ emb,
                                               float* __restrict__ ne,
                                               unsigned int* __restrict__ counts) {
#pragma clang fp contract(off)
    int k = blockIdx.x * 256 + threadIdx.x;
    if (k >= KEMB) return;
    counts[k] = 0u;
    float v[DEMB];
#pragma unroll
    for (int d = 0; d < DEMB; ++d) v[d] = emb[k * DEMB + d];
    // numpy pairwise sum, n=64: 8 strided accumulators then tree combine
    float r[8];
#pragma unroll
    for (int j = 0; j < 8; ++j) r[j] = v[j] * v[j];
#pragma unroll
    for (int i = 8; i < 64; i += 8)
#pragma unroll
        for (int j = 0; j < 8; ++j) r[j] = r[j] + v[i + j] * v[i + j];
    ne[k] = ((r[0] + r[1]) + (r[2] + r[3])) + ((r[4] + r[5]) + (r[6] + r[7]));
}

__global__ __launch_bounds__(256, 6) void vq_main(const float* __restrict__ lat,
                                                  const float* __restrict__ emb,
                                                  const float* __restrict__ ne,
                                                  float* __restrict__ outq,
                                                  float* __restrict__ onehot,
                                                  unsigned int* __restrict__ counts,
                                                  float* __restrict__ partials) {
    __shared__ float xls[64 * XS];        // 16,640 B
    __shared__ float sbest[4][64];
    __shared__ int sbi[4][64];

    const int lane = threadIdx.x & 63;
    const int wq = __builtin_amdgcn_readfirstlane(threadIdx.x >> 6); // 0..3, SGPR
    const int n0 = blockIdx.x * 64;       // first row of this block
    const int bimg = n0 >> 12;            // 4096 rows per image
    const int hw0 = n0 & 4095;

    // Stage x tile: wave wq loads d in [wq*16, wq*16+16) for all 64 rows.
    // Global: for fixed d, 64 lanes read consecutive hw -> 256B coalesced.
    // LDS write banks: (lane*65 + d)%32 = (lane+d)%32 -> 2-way, free.
    {
        const float* latp = lat + (size_t)bimg * (DEMB * 4096) + hw0 + lane;
#pragma unroll
        for (int dd = 0; dd < 16; ++dd) {
            int d = (wq << 4) + dd;
            xls[lane * XS + d] = latp[(size_t)d * 4096];
        }
    }
    __syncthreads();

    const float* xl = &xls[lane * XS];    // this lane's row (row = lane)

    // nx = ||x||^2 in numpy pairwise-8 order, no FMA contraction.
    float nx;
    {
#pragma clang fp contract(off)
        float r[8];
#pragma unroll
        for (int j = 0; j < 8; ++j) { float v = xl[j]; r[j] = v * v; }
#pragma unroll
        for (int i = 8; i < 64; i += 8)
#pragma unroll
            for (int j = 0; j < 8; ++j) { float v = xl[i + j]; r[j] = r[j] + v * v; }
        nx = ((r[0] + r[1]) + (r[2] + r[3])) + ((r[4] + r[5]) + (r[6] + r[7]));
    }

    // k-quarter loop: 64 tiles of 4 contiguous codes (1KB of emb per tile,
    // wave-uniform addresses). dot = sequential FMA chain over d per code
    // (ascending d via ascending 8-chunks = numpy BLAS micro-kernel order).
    // x re-read from LDS per chunk (DS pipe, overlaps VALU).
    // Interleaved: 2 one_hot zero-fill stores per tile (overlap HBM w/ VALU).
    float2* ohf2 = (float2*)onehot;
    const float2 z2 = make_float2(0.0f, 0.0f);
    float best = __builtin_inff();
    int bi = 0;
    const int kbase = wq << 8;
    const float* ep = emb + (size_t)kbase * DEMB;
    const float* nep = ne + kbase;
    for (int t = 0; t < 64; ++t) {
        const float* et = ep + (t << 8);  // 4 codes * 64 floats
        float a0 = 0.0f, a1 = 0.0f, a2 = 0.0f, a3 = 0.0f;
#pragma unroll
        for (int c = 0; c < 8; ++c) {
            // x chunk: 8 floats from LDS, banks (lane + 8c+j)%32 -> free
            float x0 = xl[8 * c + 0], x1 = xl[8 * c + 1];
            float x2 = xl[8 * c + 2], x3 = xl[8 * c + 3];
            float x4 = xl[8 * c + 4], x5 = xl[8 * c + 5];
            float x6 = xl[8 * c + 6], x7 = xl[8 * c + 7];
            const float4* e0q = (const float4*)(et + 8 * c);
            const float4* e1q = (const float4*)(et + 64 + 8 * c);
            const float4* e2q = (const float4*)(et + 128 + 8 * c);
            const float4* e3q = (const float4*)(et + 192 + 8 * c);
            float4 ea0 = e0q[0], eb0 = e0q[1];
            float4 ea1 = e1q[0], eb1 = e1q[1];
            float4 ea2 = e2q[0], eb2 = e2q[1];
            float4 ea3 = e3q[0], eb3 = e3q[1];
            a0 = __builtin_fmaf(x0, ea0.x, a0);
            a0 = __builtin_fmaf(x1, ea0.y, a0);
            a0 = __builtin_fmaf(x2, ea0.z, a0);
            a0 = __builtin_fmaf(x3, ea0.w, a0);
            a0 = __builtin_fmaf(x4, eb0.x, a0);
            a0 = __builtin_fmaf(x5, eb0.y, a0);
            a0 = __builtin_fmaf(x6, eb0.z, a0);
            a0 = __builtin_fmaf(x7, eb0.w, a0);
            a1 = __builtin_fmaf(x0, ea1.x, a1);
            a1 = __builtin_fmaf(x1, ea1.y, a1);
            a1 = __builtin_fmaf(x2, ea1.z, a1);
            a1 = __builtin_fmaf(x3, ea1.w, a1);
            a1 = __builtin_fmaf(x4, eb1.x, a1);
            a1 = __builtin_fmaf(x5, eb1.y, a1);
            a1 = __builtin_fmaf(x6, eb1.z, a1);
            a1 = __builtin_fmaf(x7, eb1.w, a1);
            a2 = __builtin_fmaf(x0, ea2.x, a2);
            a2 = __builtin_fmaf(x1, ea2.y, a2);
            a2 = __builtin_fmaf(x2, ea2.z, a2);
            a2 = __builtin_fmaf(x3, ea2.w, a2);
            a2 = __builtin_fmaf(x4, eb2.x, a2);
            a2 = __builtin_fmaf(x5, eb2.y, a2);
            a2 = __builtin_fmaf(x6, eb2.z, a2);
            a2 = __builtin_fmaf(x7, eb2.w, a2);
            a3 = __builtin_fmaf(x0, ea3.x, a3);
            a3 = __builtin_fmaf(x1, ea3.y, a3);
            a3 = __builtin_fmaf(x2, ea3.z, a3);
            a3 = __builtin_fmaf(x3, ea3.w, a3);
            a3 = __builtin_fmaf(x4, eb3.x, a3);
            a3 = __builtin_fmaf(x5, eb3.y, a3);
            a3 = __builtin_fmaf(x6, eb3.z, a3);
            a3 = __builtin_fmaf(x7, eb3.w, a3);
        }
        {
#pragma clang fp contract(off)
            const int k0 = kbase + (t << 2);
            float d0 = (nx + nep[t * 4 + 0]) - 2.0f * a0;
            float d1 = (nx + nep[t * 4 + 1]) - 2.0f * a1;
            float d2 = (nx + nep[t * 4 + 2]) - 2.0f * a2;
            float d3 = (nx + nep[t * 4 + 3]) - 2.0f * a3;
            if (d0 < best) { best = d0; bi = k0 + 0; }
            if (d1 < best) { best = d1; bi = k0 + 1; }
            if (d2 < best) { best = d2; bi = k0 + 2; }
            if (d3 < best) { best = d3; bi = k0 + 3; }
        }
        // zero-fill: wave wq covers one_hot chunks [wq*128, wq*128+128) of
        // row (n0+t); one row per tile, 64 tiles = all 64 rows.
        float2* zp = ohf2 + (((size_t)(n0 + t)) << 9) + (wq << 7) + lane;
        zp[0] = z2;
        zp[64] = z2;
    }

    sbest[wq][lane] = best;
    sbi[wq][lane] = bi;
    __syncthreads();   // also drains vmcnt -> all zero stores complete

    // combine quarters in ascending order, strict < (first-index tie-break)
    float bb = sbest[0][lane];
    int ib = sbi[0][lane];
#pragma unroll
    for (int qq = 1; qq < 4; ++qq) {
        float c = sbest[qq][lane];
        int ci = sbi[qq][lane];
        if (c < bb) { bb = c; ib = ci; }
    }

    if (wq == 0) {
        onehot[(size_t)(n0 + lane) * KEMB + ib] = 1.0f;
        atomicAdd(&counts[ib], 1u);
    }

    // out = lat + (q - lat); loss partial. Wave wq handles d in [wq*16,+16).
    float lsum = 0.0f;
    const size_t obase = (size_t)bimg * (DEMB * 4096) + hw0 + lane;
    {
#pragma clang fp contract(off)
        const float4* eq4 = (const float4*)(emb + (size_t)ib * DEMB + (wq << 4));
#pragma unroll
        for (int c4 = 0; c4 < 4; ++c4) {
            float4 qv = eq4[c4];
            int dbase = (wq << 4) + 4 * c4;
            float xv0 = xl[dbase + 0];
            float xv1 = xl[dbase + 1];
            float xv2 = xl[dbase + 2];
            float xv3 = xl[dbase + 3];
            float f0 = qv.x - xv0, f1 = qv.y - xv1;
            float f2 = qv.z - xv2, f3 = qv.w - xv3;
            outq[obase + (size_t)(dbase + 0) * 4096] = xv0 + f0;
            outq[obase + (size_t)(dbase + 1) * 4096] = xv1 + f1;
            outq[obase + (size_t)(dbase + 2) * 4096] = xv2 + f2;
            outq[obase + (size_t)(dbase + 3) * 4096] = xv3 + f3;
            lsum = lsum + f0 * f0;
            lsum = lsum + f1 * f1;
            lsum = lsum + f2 * f2;
            lsum = lsum + f3 * f3;
        }
    }
#pragma unroll
    for (int off = 32; off > 0; off >>= 1) lsum += __shfl_xor(lsum, off, 64);
    if (lane == 0) partials[blockIdx.x * 4 + wq] = lsum;
}

__global__ __launch_bounds__(1024) void vq_final(const unsigned int* __restrict__ counts,
                                                 const float* __restrict__ partials,
                                                 float* __restrict__ out01) {
    __shared__ float sb[1024];
    int t = threadIdx.x;
    // vq_loss: deterministic tree over 8192 per-wave partials
    float s = 0.0f;
#pragma unroll
    for (int i = 0; i < 8; ++i) s += partials[t + 1024 * i];
    sb[t] = s;
    __syncthreads();
    for (int off = 512; off > 0; off >>= 1) {
        if (t < off) sb[t] = sb[t] + sb[t + off];
        __syncthreads();
    }
    if (t == 0) {
        float m = sb[0] / 8388608.0f;   // mean of (q-lat)^2
        out01[0] = m * 0.25f + m;       // BETA*commitment + embedding
    }
    __syncthreads();
    // perplexity: avg_probs = counts / N (exact), entropy tree, exp.
    float p = (float)counts[t] * (1.0f / 131072.0f);
    sb[t] = p * logf(p + 1e-10f);
    __syncthreads();
    for (int off = 512; off > 0; off >>= 1) {
        if (t < off) sb[t] = sb[t] + sb[t + off];
        __syncthreads();
    }
    if (t == 0) out01[1] = expf(-sb[0]);
}

extern "C" void kernel_launch(void* const* d_in, const int* in_sizes, int n_in,
                              void* d_out, int out_size, void* d_ws, size_t ws_size,
                              hipStream_t stream) {
    const float* lat = (const float*)d_in[0];
    const float* emb = (const float*)d_in[1];
    float* out = (float*)d_out;
    float* ws = (float*)d_ws;

    float* ne = ws;
    unsigned int* counts = (unsigned int*)(ws + 1024);
    float* partials = ws + 2048;

    float* outq = out + 2;
    float* onehot = out + 2 + 8388608;

    vq_prep<<<4, 256, 0, stream>>>(emb, ne, counts);
    vq_main<<<2048, 256, 0, stream>>>(lat, emb, ne, outq, onehot, counts, partials);
    vq_final<<<1, 1024, 0, stream>>>(counts, partials, out);
}